// Round 9
// baseline (281.850 us; speedup 1.0000x reference)
//
#include <hip/hip_runtime.h>
#include <math.h>

#define NWAVE   8
#define NATOMS  16384
#define NPAIRS  524288
#define NSPEC   117
#define TBLN    (NSPEC * NSPEC)
#define NPADC   (NPAIRS + NATOMS * 8)   // 655360 max padded slots
#define APB     16                      // atoms per block in pass kernels
#define CBLK    (NATOMS / 4)
#define TBLK    ((TBLN + 3) / 4)

typedef unsigned short ushort_t;
typedef unsigned int uint_t;

// ---------- helpers ----------
__device__ __forceinline__ float wred_sum(float v) {
#pragma unroll
    for (int o = 1; o < 64; o <<= 1) v += __shfl_xor(v, o, 64);
    return v;
}

__device__ __forceinline__ float ln_silu(float h, float gg, float bb) {
    float m = wred_sum(h) * (1.f / 64.f);
    float c = h - m;
    float v = wred_sum(c * c) * (1.f / 64.f);
    float y = c * rsqrtf(v + 1e-5f) * gg + bb;
    return y / (1.f + expf(-y));
}

__device__ __forceinline__ float dot4(float4 a, float4 b) {
    return a.x * b.x + a.y * b.y + a.z * b.z + a.w * b.w;
}

__device__ __forceinline__ ushort_t f2bf(float x) {
    uint_t u = __float_as_uint(x);
    u += 0x7FFF + ((u >> 16) & 1);
    return (ushort_t)(u >> 16);
}
__device__ __forceinline__ float bf2f(ushort_t s) {
    return __uint_as_float(((uint_t)s) << 16);
}

// ---------- k_hist: histogram + dist_vec output + plist init ----------
__global__ void k_hist(const int* __restrict__ aidx, const float* __restrict__ cart,
                       int* __restrict__ cnt, int* __restrict__ plist,
                       float* __restrict__ dist_out) {
    int p = blockIdx.x * 256 + threadIdx.x;
    if (p < NPAIRS) {
        atomicAdd(&cnt[aidx[p]], 1);
        int i0 = aidx[p];
        int i1 = aidx[NPAIRS + p];
        float dv0 = cart[i0 * 3 + 0] - cart[i1 * 3 + 0];
        float dv1 = cart[i0 * 3 + 1] - cart[i1 * 3 + 1];
        float dv2 = cart[i0 * 3 + 2] - cart[i1 * 3 + 2];
        dist_out[(size_t)p * 3 + 0] = dv0;
        dist_out[(size_t)p * 3 + 1] = dv1;
        dist_out[(size_t)p * 3 + 2] = dv2;
    }
    for (int q = p; q < NPADC; q += NPAIRS) plist[q] = -1;
}

__global__ void k_scan(const int* __restrict__ cnt, int* __restrict__ offs,
                       int* __restrict__ cursor) {
    __shared__ int sums[1024];
    int t = threadIdx.x;
    int base = t * 16;
    int v[16];
    int s = 0;
#pragma unroll
    for (int u = 0; u < 16; u++) { v[u] = (cnt[base + u] + 7) & ~7; s += v[u]; }
    sums[t] = s;
    __syncthreads();
    for (int d = 1; d < 1024; d <<= 1) {
        int x = (t >= d) ? sums[t - d] : 0;
        __syncthreads();
        sums[t] += x;
        __syncthreads();
    }
    int run = (t == 0) ? 0 : sums[t - 1];
#pragma unroll
    for (int u = 0; u < 16; u++) {
        offs[base + u] = run;
        cursor[base + u] = run;
        run += v[u];
    }
    if (t == 1023) offs[NATOMS] = run;
}

__global__ void k_scatter(const int* __restrict__ ai0, int* __restrict__ cursor,
                          int* __restrict__ plist) {
    int p = blockIdx.x * 256 + threadIdx.x;
    if (p < NPAIRS) {
        int pos = atomicAdd(&cursor[ai0[p]], 1);
        plist[pos] = p;
    }
}

// ---------- k_emb: center MLP + table MLP, one kernel ----------
__global__ void k_emb(const int* __restrict__ spec,
                      const float* __restrict__ cW1, const float* __restrict__ cb1,
                      const float* __restrict__ cg,  const float* __restrict__ cbe,
                      const float* __restrict__ cW2, const float* __restrict__ cb2,
                      float* __restrict__ ccoef,
                      const float* __restrict__ nW1, const float* __restrict__ nb1,
                      const float* __restrict__ ng,  const float* __restrict__ nbe,
                      const float* __restrict__ nW2, const float* __restrict__ nb2,
                      float* __restrict__ table) {
    __shared__ float h_s[4][64];
    int lane = threadIdx.x & 63, slot = threadIdx.x >> 6;
    if (blockIdx.x < CBLK) {
        int atom = blockIdx.x * 4 + slot;
        int s = spec[atom] + 1;
        float h = cW1[s * 64 + lane] + cb1[lane];
        h = ln_silu(h, cg[lane], cbe[lane]);
        h_s[slot][lane] = h;
        __syncthreads();
        float o = cb2[lane];
#pragma unroll 8
        for (int i = 0; i < 64; i++) o += h_s[slot][i] * cW2[i * 64 + lane];
        ccoef[atom * 64 + lane] = o;
    } else {
        int key = (blockIdx.x - CBLK) * 4 + slot;
        int kk = (key < TBLN) ? key : 0;
        int s0 = kk / NSPEC + 1, s1 = kk % NSPEC + 1;
        float h = nW1[s0 * 64 + lane] + nW1[s1 * 64 + lane] + nb1[lane];
        h = ln_silu(h, ng[lane], nbe[lane]);
        h_s[slot][lane] = h;
        __syncthreads();
        if (lane < 24 && key < TBLN) {
            float o = nb2[lane];
#pragma unroll 8
            for (int i = 0; i < 64; i++) o += h_s[slot][i] * nW2[i * 24 + lane];
            table[key * 24 + lane] = o;
        }
    }
}

// ---------- per-pair: pair-major bf16 streams ----------
__global__ void k_pair2(const float* __restrict__ cart, const int* __restrict__ aidx,
                        const int* __restrict__ spec,  const float* __restrict__ table,
                        const int* __restrict__ plist, const int* __restrict__ total_p,
                        ushort_t* __restrict__ ang16,  ushort_t* __restrict__ rad16,
                        int* __restrict__ keyv,        int* __restrict__ neigh) {
    int pos = blockIdx.x * 256 + threadIdx.x;
    if (pos >= total_p[0]) return;
    int p = plist[pos];
    if (p < 0) {
        *(uint4*)(rad16 + (size_t)pos * 8) = make_uint4(0, 0, 0, 0);
        *(uint2*)(ang16 + (size_t)pos * 4) = make_uint2(0, 0);
        keyv[pos] = 0;
        neigh[pos] = 0;
        return;
    }
    int i0 = aidx[p];
    int i1 = aidx[NPAIRS + p];
    float dv0 = cart[i0 * 3 + 0] - cart[i1 * 3 + 0];
    float dv1 = cart[i0 * 3 + 1] - cart[i1 * 3 + 1];
    float dv2 = cart[i0 * 3 + 2] - cart[i1 * 3 + 2];
    float d = sqrtf(dv0 * dv0 + dv1 * dv1 + dv2 * dv2);

    int key = spec[i0] * NSPEC + spec[i1];
    const float4* ne = (const float4*)(table + (size_t)key * 24);
    float4 al_a = ne[2], al_b = ne[3];
    float4 mu_a = ne[4], mu_b = ne[5];

    float cth = cosf(d * (float)(M_PI / 4.0));
    float t0 = 0.5f * cth + 0.5f;
    float fc = t0 * t0;
    uint2 av;
    av.x = (uint_t)f2bf(fc) | ((uint_t)f2bf(dv0 * fc) << 16);
    av.y = (uint_t)f2bf(dv1 * fc) | ((uint_t)f2bf(dv2 * fc) << 16);
    *(uint2*)(ang16 + (size_t)pos * 4) = av;

    float r[8];
    float t;
    t = al_a.x * (d - mu_a.x); r[0] = expf(-t * t);
    t = al_a.y * (d - mu_a.y); r[1] = expf(-t * t);
    t = al_a.z * (d - mu_a.z); r[2] = expf(-t * t);
    t = al_a.w * (d - mu_a.w); r[3] = expf(-t * t);
    t = al_b.x * (d - mu_b.x); r[4] = expf(-t * t);
    t = al_b.y * (d - mu_b.y); r[5] = expf(-t * t);
    t = al_b.z * (d - mu_b.z); r[6] = expf(-t * t);
    t = al_b.w * (d - mu_b.w); r[7] = expf(-t * t);
    uint4 rv4;
    rv4.x = (uint_t)f2bf(r[0]) | ((uint_t)f2bf(r[1]) << 16);
    rv4.y = (uint_t)f2bf(r[2]) | ((uint_t)f2bf(r[3]) << 16);
    rv4.z = (uint_t)f2bf(r[4]) | ((uint_t)f2bf(r[5]) << 16);
    rv4.w = (uint_t)f2bf(r[6]) | ((uint_t)f2bf(r[7]) << 16);
    *(uint4*)(rad16 + (size_t)pos * 8) = rv4;
    keyv[pos] = key;
    neigh[pos] = i1;
}

// ---------- fused pass: lane=(slot-group,k) gather -> shfl reduce -> MLP ----------
template <bool PASS0, bool FINAL>
__global__ __launch_bounds__(256, 4)
void k_pass(const int* __restrict__ offs,
            const ushort_t* __restrict__ ang16, const ushort_t* __restrict__ rad16,
            const int* __restrict__ keyv,  const float* __restrict__ table,
            const int* __restrict__ neigh, const float* __restrict__ S_in,
            float* __restrict__ co0,       const float* __restrict__ ccenter,
            const float* __restrict__ cc_g,
            const float* __restrict__ W1,  const float* __restrict__ b1,
            const float* __restrict__ g,   const float* __restrict__ be,
            const float* __restrict__ W2,  const float* __restrict__ b2,
            const int* __restrict__ spec,  float* __restrict__ dst) {
    __shared__ float w1_s[4096];     // raw [i][o]
    __shared__ float cc_s[1024];     // raw [row][k][m]
    __shared__ float w2t_s[512];     // [o][i] (oc); first 64 = W2 vec (final)
    __shared__ float b1_s[64], g_s[64], be_s[64], b2_s[8];
    __shared__ float dens_s[4][64], h_s[4][64];

    const int t = threadIdx.x, lane = t & 63, wv = t >> 6;
    const int abase = blockIdx.x * APB;

    // ---- stage weights ----
    for (int i = t; i < 1024; i += 256) ((float4*)w1_s)[i] = ((const float4*)W1)[i];
    if (t < 256) ((float4*)cc_s)[t] = ((const float4*)cc_g)[t];
    if (FINAL) {
        if (t < 64) w2t_s[t] = W2[t];
        if (t == 64) b2_s[0] = b2[0];
    } else {
        if (t < 256) {  // transpose W2 (64x8) -> w2t (8x64)
            int i = t >> 2, o0 = (t & 3) * 2;
            w2t_s[(o0 + 0) * 64 + i] = W2[i * 8 + o0 + 0];
            w2t_s[(o0 + 1) * 64 + i] = W2[i * 8 + o0 + 1];
        }
        if (t >= 256 - 8) b2_s[t - 248] = b2[t - 248];
    }
    if (t < 64) { b1_s[t] = b1[t]; g_s[t] = g[t]; be_s[t] = be[t]; }
    __syncthreads();   // only barrier in the kernel

    const int k = lane & 7, sg = lane >> 3;

    // ---- per-wave atoms: wv, wv+4, ... ----
#pragma unroll 1
    for (int la = wv; la < APB; la += 4) {
        int atom = abase + la;
        int start = offs[atom], end = offs[atom + 1];
        float a0 = 0.f, a1 = 0.f, a2 = 0.f, a3 = 0.f;
        for (int pos = start + sg; pos < end; pos += 8) {
            float rv = bf2f(rad16[(size_t)pos * 8 + k]);
            float w;
            if (PASS0) {
                int ky = keyv[pos];
                w = table[(size_t)ky * 24 + k];
            } else {
                int n = neigh[pos];
                w = S_in[(size_t)n * 8 + k];
            }
            float rw = rv * w;
            ushort4 a4 = *(const ushort4*)(ang16 + (size_t)pos * 4);
            a0 += bf2f(a4.x) * rw;
            a1 += bf2f(a4.y) * rw;
            a2 += bf2f(a4.z) * rw;
            a3 += bf2f(a4.w) * rw;
        }
        // reduce over slot-groups: lanes with same k
#pragma unroll
        for (int o = 8; o < 64; o <<= 1) {
            a0 += __shfl_xor(a0, o, 64);
            a1 += __shfl_xor(a1, o, 64);
            a2 += __shfl_xor(a2, o, 64);
            a3 += __shfl_xor(a3, o, 64);
        }
        // lane's own (j = lane>>3 in [0,4) for lane<32, k = lane&7) value
        int jsel = lane >> 3;
        float mine = (jsel == 0) ? a0 : (jsel == 1) ? a1 : (jsel == 2) ? a2 : a3;
        if (PASS0) {
            if (lane < 32) co0[(size_t)atom * 32 + lane] = mine;
        } else {
            if (lane < 32) mine += co0[(size_t)atom * 32 + lane];
        }
        // broadcast all 32 co values to every lane
        float co[32];
#pragma unroll
        for (int i = 0; i < 32; i++) co[i] = __shfl(mine, i, 64);

        // contraction (lane = m)
        float dens = ccenter[(size_t)atom * 64 + lane];
        {
            float s = 0.f;
#pragma unroll
            for (int kk = 0; kk < 8; kk++) s += co[kk] * cc_s[kk * 64 + lane];
            dens += s * s;
        }
#pragma unroll
        for (int jj = 1; jj < 4; jj++) {
            float s = 0.f;
#pragma unroll
            for (int kk = 0; kk < 8; kk++) s += co[jj * 8 + kk] * cc_s[512 + kk * 64 + lane];
            dens += s * s;
        }
        dens_s[wv][lane] = dens;   // wave-private row: no barrier needed

        float h = b1_s[lane];
        const float4* dp = (const float4*)dens_s[wv];
#pragma unroll
        for (int q = 0; q < 16; q++) {
            float4 dv = dp[q];
            h += dv.x * w1_s[(q * 4 + 0) * 64 + lane]
               + dv.y * w1_s[(q * 4 + 1) * 64 + lane]
               + dv.z * w1_s[(q * 4 + 2) * 64 + lane]
               + dv.w * w1_s[(q * 4 + 3) * 64 + lane];
        }
        h = ln_silu(h, g_s[lane], be_s[lane]);

        if (FINAL) {
            float s = wred_sum(h * w2t_s[lane]);
            if (lane == 0) {
                float mask = (spec[atom] >= 0) ? 1.f : 0.f;
                dst[atom] = (s + b2_s[0]) * mask;
            }
        } else {
            h_s[wv][lane] = h;     // wave-private row
            int o = lane >> 3, seg = lane & 7;
            const float4* w2p = (const float4*)(w2t_s + o * 64 + seg * 8);
            const float4* hp  = (const float4*)(&h_s[wv][seg * 8]);
            float part = dot4(w2p[0], hp[0]) + dot4(w2p[1], hp[1]);
            part += __shfl_xor(part, 1, 64);
            part += __shfl_xor(part, 2, 64);
            part += __shfl_xor(part, 4, 64);
            if (seg == 0) {
                float val = part + b2_s[o];
                if (!PASS0) val += S_in[(size_t)atom * 8 + o];
                dst[(size_t)atom * 8 + o] = val;
            }
        }
    }
}

extern "C" void kernel_launch(void* const* d_in, const int* in_sizes, int n_in,
                              void* d_out, int out_size, void* d_ws, size_t ws_size,
                              hipStream_t stream) {
    const float* cart   = (const float*)d_in[0];
    const int*   aidx   = (const int*)d_in[1];
    const int*   spec   = (const int*)d_in[2];
    const float* ccoeff = (const float*)d_in[4];
    const float* embn_W1 = (const float*)d_in[5];
    const float* embn_b1 = (const float*)d_in[6];
    const float* embn_g  = (const float*)d_in[7];
    const float* embn_be = (const float*)d_in[8];
    const float* embn_W2 = (const float*)d_in[9];
    const float* embn_b2 = (const float*)d_in[10];
    const float* embc_W1 = (const float*)d_in[11];
    const float* embc_b1 = (const float*)d_in[12];
    const float* embc_g  = (const float*)d_in[13];
    const float* embc_be = (const float*)d_in[14];
    const float* embc_W2 = (const float*)d_in[15];
    const float* embc_b2 = (const float*)d_in[16];
    const float* oc_W1 = (const float*)d_in[17];
    const float* oc_b1 = (const float*)d_in[18];
    const float* oc_g  = (const float*)d_in[19];
    const float* oc_be = (const float*)d_in[20];
    const float* oc_W2 = (const float*)d_in[21];
    const float* oc_b2 = (const float*)d_in[22];
    const float* out_W1 = (const float*)d_in[23];
    const float* out_b1 = (const float*)d_in[24];
    const float* out_g  = (const float*)d_in[25];
    const float* out_be = (const float*)d_in[26];
    const float* out_W2 = (const float*)d_in[27];
    const float* out_b2 = (const float*)d_in[28];

    float* outp = (float*)d_out;

    char* ws = (char*)d_ws;
    size_t off = 0;
    auto carve = [&](size_t bytes) { size_t o = off; off = (off + bytes + 255) & ~(size_t)255; return o; };
    ushort_t* ang16 = (ushort_t*)(ws + carve((size_t)NPADC * 4 * 2));
    ushort_t* rad16 = (ushort_t*)(ws + carve((size_t)NPADC * 8 * 2));
    int*   keyv    = (int*)(ws + carve((size_t)NPADC * 4));
    int*   neigh   = (int*)(ws + carve((size_t)NPADC * 4));
    int*   plist   = (int*)(ws + carve((size_t)NPADC * 4));
    float* ccenter = (float*)(ws + carve((size_t)NATOMS * 64 * 4));
    float* co0     = (float*)(ws + carve((size_t)NATOMS * 32 * 4));
    float* Sa      = (float*)(ws + carve((size_t)NATOMS * 8 * 4));
    float* Sb      = (float*)(ws + carve((size_t)NATOMS * 8 * 4));
    float* table   = (float*)(ws + carve((size_t)TBLN * 24 * 4));
    int*   cnt     = (int*)(ws + carve((size_t)NATOMS * 4));
    int*   offs    = (int*)(ws + carve((size_t)(NATOMS + 1) * 4));
    int*   cursor  = (int*)(ws + carve((size_t)NATOMS * 4));

    hipMemsetAsync(cnt, 0, (size_t)NATOMS * 4, stream);
    k_hist<<<NPAIRS / 256, 256, 0, stream>>>(aidx, cart, cnt, plist, outp);
    k_scan<<<1, 1024, 0, stream>>>(cnt, offs, cursor);
    k_scatter<<<NPAIRS / 256, 256, 0, stream>>>(aidx, cursor, plist);

    k_emb<<<CBLK + TBLK, 256, 0, stream>>>(spec,
                                           embc_W1, embc_b1, embc_g, embc_be, embc_W2, embc_b2,
                                           ccenter,
                                           embn_W1, embn_b1, embn_g, embn_be, embn_W2, embn_b2,
                                           table);

    k_pair2<<<NPADC / 256, 256, 0, stream>>>(cart, aidx, spec, table, plist, offs + NATOMS,
                                             ang16, rad16, keyv, neigh);

    // pass 0: co0 + oc0 -> Sa
    k_pass<true, false><<<NATOMS / APB, 256, 0, stream>>>(
        offs, ang16, rad16, keyv, table, neigh, nullptr, co0, ccenter,
        ccoeff + 0 * 1024, oc_W1 + 0 * 4096, oc_b1 + 0 * 64, oc_g + 0 * 64,
        oc_be + 0 * 64, oc_W2 + 0 * 512, oc_b2 + 0 * 8, spec, Sa);
    // pass 1: S=Sa -> Sb (= Sa + oc1)
    k_pass<false, false><<<NATOMS / APB, 256, 0, stream>>>(
        offs, ang16, rad16, keyv, table, neigh, Sa, co0, ccenter,
        ccoeff + 1 * 1024, oc_W1 + 1 * 4096, oc_b1 + 1 * 64, oc_g + 1 * 64,
        oc_be + 1 * 64, oc_W2 + 1 * 512, oc_b2 + 1 * 8, spec, Sb);
    // pass 2: S=Sb -> Sa (= Sb + oc2)
    k_pass<false, false><<<NATOMS / APB, 256, 0, stream>>>(
        offs, ang16, rad16, keyv, table, neigh, Sb, co0, ccenter,
        ccoeff + 2 * 1024, oc_W1 + 2 * 4096, oc_b1 + 2 * 64, oc_g + 2 * 64,
        oc_be + 2 * 64, oc_W2 + 2 * 512, oc_b2 + 2 * 8, spec, Sa);
    // final: S=Sa -> output
    k_pass<false, true><<<NATOMS / APB, 256, 0, stream>>>(
        offs, ang16, rad16, keyv, table, neigh, Sa, co0, ccenter,
        ccoeff + 3 * 1024, out_W1, out_b1, out_g, out_be,
        out_W2, out_b2, spec, outp + (size_t)NPAIRS * 3);
}

// Round 10
// 243.737 us; speedup vs baseline: 1.1564x; 1.1564x over previous
//
#include <hip/hip_runtime.h>
#include <math.h>

#define NWAVE   8
#define NATOMS  16384
#define NPAIRS  524288
#define NSPEC   117
#define TBLN    (NSPEC * NSPEC)
#define NPADC   (NPAIRS + NATOMS * 8)   // 655360 max padded slots
#define CBLK    (NATOMS / 4)
#define TBLK    ((TBLN + 3) / 4)
#define AMLP    32                      // atoms per block in k_mlp

typedef unsigned short ushort_t;
typedef unsigned int uint_t;

// ---------- helpers ----------
__device__ __forceinline__ float wred_sum(float v) {
#pragma unroll
    for (int o = 1; o < 64; o <<= 1) v += __shfl_xor(v, o, 64);
    return v;
}

__device__ __forceinline__ float ln_silu(float h, float gg, float bb) {
    float m = wred_sum(h) * (1.f / 64.f);
    float c = h - m;
    float v = wred_sum(c * c) * (1.f / 64.f);
    float y = c * rsqrtf(v + 1e-5f) * gg + bb;
    return y / (1.f + expf(-y));
}

__device__ __forceinline__ float dot4(float4 a, float4 b) {
    return a.x * b.x + a.y * b.y + a.z * b.z + a.w * b.w;
}

__device__ __forceinline__ ushort_t f2bf(float x) {
    uint_t u = __float_as_uint(x);
    u += 0x7FFF + ((u >> 16) & 1);
    return (ushort_t)(u >> 16);
}
__device__ __forceinline__ float bf2f(ushort_t s) {
    return __uint_as_float(((uint_t)s) << 16);
}

// ---------- k_hist: histogram + dist_vec output + plist init ----------
__global__ void k_hist(const int* __restrict__ aidx, const float* __restrict__ cart,
                       int* __restrict__ cnt, int* __restrict__ plist,
                       float* __restrict__ dist_out) {
    int p = blockIdx.x * 256 + threadIdx.x;
    if (p < NPAIRS) {
        atomicAdd(&cnt[aidx[p]], 1);
        int i0 = aidx[p];
        int i1 = aidx[NPAIRS + p];
        float dv0 = cart[i0 * 3 + 0] - cart[i1 * 3 + 0];
        float dv1 = cart[i0 * 3 + 1] - cart[i1 * 3 + 1];
        float dv2 = cart[i0 * 3 + 2] - cart[i1 * 3 + 2];
        dist_out[(size_t)p * 3 + 0] = dv0;
        dist_out[(size_t)p * 3 + 1] = dv1;
        dist_out[(size_t)p * 3 + 2] = dv2;
    }
    for (int q = p; q < NPADC; q += NPAIRS) plist[q] = -1;
}

__global__ void k_scan(const int* __restrict__ cnt, int* __restrict__ offs,
                       int* __restrict__ cursor) {
    __shared__ int sums[1024];
    int t = threadIdx.x;
    int base = t * 16;
    int v[16];
    int s = 0;
#pragma unroll
    for (int u = 0; u < 16; u++) { v[u] = (cnt[base + u] + 7) & ~7; s += v[u]; }
    sums[t] = s;
    __syncthreads();
    for (int d = 1; d < 1024; d <<= 1) {
        int x = (t >= d) ? sums[t - d] : 0;
        __syncthreads();
        sums[t] += x;
        __syncthreads();
    }
    int run = (t == 0) ? 0 : sums[t - 1];
#pragma unroll
    for (int u = 0; u < 16; u++) {
        offs[base + u] = run;
        cursor[base + u] = run;
        run += v[u];
    }
    if (t == 1023) offs[NATOMS] = run;
}

__global__ void k_scatter(const int* __restrict__ ai0, int* __restrict__ cursor,
                          int* __restrict__ plist) {
    int p = blockIdx.x * 256 + threadIdx.x;
    if (p < NPAIRS) {
        int pos = atomicAdd(&cursor[ai0[p]], 1);
        plist[pos] = p;
    }
}

// ---------- k_emb: center MLP + table MLP, one kernel ----------
__global__ void k_emb(const int* __restrict__ spec,
                      const float* __restrict__ cW1, const float* __restrict__ cb1,
                      const float* __restrict__ cg,  const float* __restrict__ cbe,
                      const float* __restrict__ cW2, const float* __restrict__ cb2,
                      float* __restrict__ ccoef,
                      const float* __restrict__ nW1, const float* __restrict__ nb1,
                      const float* __restrict__ ng,  const float* __restrict__ nbe,
                      const float* __restrict__ nW2, const float* __restrict__ nb2,
                      float* __restrict__ table) {
    __shared__ float h_s[4][64];
    int lane = threadIdx.x & 63, slot = threadIdx.x >> 6;
    if (blockIdx.x < CBLK) {
        int atom = blockIdx.x * 4 + slot;
        int s = spec[atom] + 1;
        float h = cW1[s * 64 + lane] + cb1[lane];
        h = ln_silu(h, cg[lane], cbe[lane]);
        h_s[slot][lane] = h;
        __syncthreads();
        float o = cb2[lane];
#pragma unroll 8
        for (int i = 0; i < 64; i++) o += h_s[slot][i] * cW2[i * 64 + lane];
        ccoef[atom * 64 + lane] = o;
    } else {
        int key = (blockIdx.x - CBLK) * 4 + slot;
        int kk = (key < TBLN) ? key : 0;
        int s0 = kk / NSPEC + 1, s1 = kk % NSPEC + 1;
        float h = nW1[s0 * 64 + lane] + nW1[s1 * 64 + lane] + nb1[lane];
        h = ln_silu(h, ng[lane], nbe[lane]);
        h_s[slot][lane] = h;
        __syncthreads();
        if (lane < 24 && key < TBLN) {
            float o = nb2[lane];
#pragma unroll 8
            for (int i = 0; i < 64; i++) o += h_s[slot][i] * nW2[i * 24 + lane];
            table[key * 24 + lane] = o;
        }
    }
}

// ---------- per-pair: planar bf16 streams ----------
__global__ void k_pair2(const float* __restrict__ cart, const int* __restrict__ aidx,
                        const int* __restrict__ spec,  const float* __restrict__ table,
                        const int* __restrict__ plist, const int* __restrict__ total_p,
                        ushort_t* __restrict__ ang16,  ushort_t* __restrict__ rad16,
                        int* __restrict__ keyv,        int* __restrict__ neigh) {
    int pos = blockIdx.x * 256 + threadIdx.x;
    if (pos >= total_p[0]) return;
    int p = plist[pos];
    if (p < 0) {
#pragma unroll
        for (int j = 0; j < 4; j++) ang16[(size_t)j * NPADC + pos] = 0;
#pragma unroll
        for (int k = 0; k < 8; k++) rad16[(size_t)k * NPADC + pos] = 0;
        keyv[pos] = 0;
        neigh[pos] = 0;
        return;
    }
    int i0 = aidx[p];
    int i1 = aidx[NPAIRS + p];
    float dv0 = cart[i0 * 3 + 0] - cart[i1 * 3 + 0];
    float dv1 = cart[i0 * 3 + 1] - cart[i1 * 3 + 1];
    float dv2 = cart[i0 * 3 + 2] - cart[i1 * 3 + 2];
    float d = sqrtf(dv0 * dv0 + dv1 * dv1 + dv2 * dv2);

    int key = spec[i0] * NSPEC + spec[i1];
    const float4* ne = (const float4*)(table + (size_t)key * 24);
    float4 al_a = ne[2], al_b = ne[3];
    float4 mu_a = ne[4], mu_b = ne[5];

    float cth = cosf(d * (float)(M_PI / 4.0));
    float t0 = 0.5f * cth + 0.5f;
    float fc = t0 * t0;
    ang16[(size_t)0 * NPADC + pos] = f2bf(fc);
    ang16[(size_t)1 * NPADC + pos] = f2bf(dv0 * fc);
    ang16[(size_t)2 * NPADC + pos] = f2bf(dv1 * fc);
    ang16[(size_t)3 * NPADC + pos] = f2bf(dv2 * fc);

    float r[8];
    float t;
    t = al_a.x * (d - mu_a.x); r[0] = expf(-t * t);
    t = al_a.y * (d - mu_a.y); r[1] = expf(-t * t);
    t = al_a.z * (d - mu_a.z); r[2] = expf(-t * t);
    t = al_a.w * (d - mu_a.w); r[3] = expf(-t * t);
    t = al_b.x * (d - mu_b.x); r[4] = expf(-t * t);
    t = al_b.y * (d - mu_b.y); r[5] = expf(-t * t);
    t = al_b.z * (d - mu_b.z); r[6] = expf(-t * t);
    t = al_b.w * (d - mu_b.w); r[7] = expf(-t * t);
#pragma unroll
    for (int k = 0; k < 8; k++) rad16[(size_t)k * NPADC + pos] = f2bf(r[k]);
    keyv[pos] = key;
    neigh[pos] = i1;
}

// ---------- gather kernel: half-wave per atom, no LDS, high occupancy ----------
template <bool PASS0>
__global__ __launch_bounds__(256, 6)
void k_co(const int* __restrict__ offs,
          const ushort_t* __restrict__ ang16, const ushort_t* __restrict__ rad16,
          const int* __restrict__ keyv,  const float* __restrict__ table,
          const int* __restrict__ neigh, const float* __restrict__ S_in,
          const float* __restrict__ co0, float* __restrict__ co_out) {
    int lane = threadIdx.x & 63, wv = threadIdx.x >> 6;
    int la = wv * 2 + (lane >> 5);               // 0..7
    int atom = blockIdx.x * 8 + la;
    int start = offs[atom], end = offs[atom + 1];
    int jk = lane & 31, j = jk >> 3, k = jk & 7;
    const ushort_t* aj = ang16 + (size_t)j * NPADC + start;
    const ushort_t* rk = rad16 + (size_t)k * NPADC + start;
    float acc = 0.f;
    if (PASS0) {
        const int* kb = keyv + start;
        for (int q = 0; q < end - start; q += 8) {
            ushort4 a0 = *(const ushort4*)(aj + q), a1 = *(const ushort4*)(aj + q + 4);
            ushort4 r0 = *(const ushort4*)(rk + q), r1 = *(const ushort4*)(rk + q + 4);
            int4 k0 = *(const int4*)(kb + q), k1 = *(const int4*)(kb + q + 4);
            float w0 = table[(size_t)k0.x * 24 + k];
            float w1 = table[(size_t)k0.y * 24 + k];
            float w2 = table[(size_t)k0.z * 24 + k];
            float w3 = table[(size_t)k0.w * 24 + k];
            float w4 = table[(size_t)k1.x * 24 + k];
            float w5 = table[(size_t)k1.y * 24 + k];
            float w6 = table[(size_t)k1.z * 24 + k];
            float w7 = table[(size_t)k1.w * 24 + k];
            acc += bf2f(a0.x) * bf2f(r0.x) * w0 + bf2f(a0.y) * bf2f(r0.y) * w1
                 + bf2f(a0.z) * bf2f(r0.z) * w2 + bf2f(a0.w) * bf2f(r0.w) * w3
                 + bf2f(a1.x) * bf2f(r1.x) * w4 + bf2f(a1.y) * bf2f(r1.y) * w5
                 + bf2f(a1.z) * bf2f(r1.z) * w6 + bf2f(a1.w) * bf2f(r1.w) * w7;
        }
        co_out[(size_t)atom * 32 + jk] = acc;
    } else {
        const int* nbp = neigh + start;
        for (int q = 0; q < end - start; q += 8) {
            ushort4 a0 = *(const ushort4*)(aj + q), a1 = *(const ushort4*)(aj + q + 4);
            ushort4 r0 = *(const ushort4*)(rk + q), r1 = *(const ushort4*)(rk + q + 4);
            int4 n0 = *(const int4*)(nbp + q), n1 = *(const int4*)(nbp + q + 4);
            float w0 = S_in[(size_t)n0.x * 8 + k];
            float w1 = S_in[(size_t)n0.y * 8 + k];
            float w2 = S_in[(size_t)n0.z * 8 + k];
            float w3 = S_in[(size_t)n0.w * 8 + k];
            float w4 = S_in[(size_t)n1.x * 8 + k];
            float w5 = S_in[(size_t)n1.y * 8 + k];
            float w6 = S_in[(size_t)n1.z * 8 + k];
            float w7 = S_in[(size_t)n1.w * 8 + k];
            acc += bf2f(a0.x) * bf2f(r0.x) * w0 + bf2f(a0.y) * bf2f(r0.y) * w1
                 + bf2f(a0.z) * bf2f(r0.z) * w2 + bf2f(a0.w) * bf2f(r0.w) * w3
                 + bf2f(a1.x) * bf2f(r1.x) * w4 + bf2f(a1.y) * bf2f(r1.y) * w5
                 + bf2f(a1.z) * bf2f(r1.z) * w6 + bf2f(a1.w) * bf2f(r1.w) * w7;
        }
        co_out[(size_t)atom * 32 + jk] = acc + co0[(size_t)atom * 32 + jk];
    }
}

// ---------- MLP kernel: contraction + MLP, weights LDS-staged, AMLP atoms/block ----------
template <bool PASS0, bool FINAL>
__global__ __launch_bounds__(256)
void k_mlp(const float* __restrict__ co, const float* __restrict__ ccenter,
           const float* __restrict__ cc_g,
           const float* __restrict__ W1, const float* __restrict__ b1,
           const float* __restrict__ g,  const float* __restrict__ be,
           const float* __restrict__ W2, const float* __restrict__ b2,
           const float* __restrict__ S_in, const int* __restrict__ spec,
           float* __restrict__ dst) {
    __shared__ float w1_s[4096];     // raw [i][o]
    __shared__ float cc_s[1024];     // raw [row][k][m]
    __shared__ float w2t_s[512];     // [o][i] (oc); first 64 = W2 vec (final)
    __shared__ float b1_s[64], g_s[64], be_s[64], b2_s[8];
    __shared__ float co_s[4][32], dens_s[4][64], h_s[4][64];

    const int t = threadIdx.x, lane = t & 63, wv = t >> 6;
    const int abase = blockIdx.x * AMLP;

    for (int i = t; i < 1024; i += 256) ((float4*)w1_s)[i] = ((const float4*)W1)[i];
    if (t < 256) ((float4*)cc_s)[t] = ((const float4*)cc_g)[t];
    if (FINAL) {
        if (t < 64) w2t_s[t] = W2[t];
        if (t == 64) b2_s[0] = b2[0];
    } else {
        if (t < 256) {  // transpose W2 (64x8) -> w2t (8x64)
            int i = t >> 2, o0 = (t & 3) * 2;
            w2t_s[(o0 + 0) * 64 + i] = W2[i * 8 + o0 + 0];
            w2t_s[(o0 + 1) * 64 + i] = W2[i * 8 + o0 + 1];
        }
        if (t >= 256 - 8) b2_s[t - 248] = b2[t - 248];
    }
    if (t < 64) { b1_s[t] = b1[t]; g_s[t] = g[t]; be_s[t] = be[t]; }
    __syncthreads();

#pragma unroll 1
    for (int la = wv; la < AMLP; la += 4) {
        int atom = abase + la;
        if (lane < 32) co_s[wv][lane] = co[(size_t)atom * 32 + lane];  // wave-private row

        float dens = ccenter[(size_t)atom * 64 + lane];
        {
            float s = 0.f;
#pragma unroll
            for (int kk = 0; kk < 8; kk++) s += co_s[wv][kk] * cc_s[kk * 64 + lane];
            dens += s * s;
        }
#pragma unroll
        for (int jj = 1; jj < 4; jj++) {
            float s = 0.f;
#pragma unroll
            for (int kk = 0; kk < 8; kk++)
                s += co_s[wv][jj * 8 + kk] * cc_s[512 + kk * 64 + lane];
            dens += s * s;
        }
        dens_s[wv][lane] = dens;   // wave-private row

        float h = b1_s[lane];
        const float4* dp = (const float4*)dens_s[wv];
#pragma unroll
        for (int q = 0; q < 16; q++) {
            float4 dv = dp[q];
            h += dv.x * w1_s[(q * 4 + 0) * 64 + lane]
               + dv.y * w1_s[(q * 4 + 1) * 64 + lane]
               + dv.z * w1_s[(q * 4 + 2) * 64 + lane]
               + dv.w * w1_s[(q * 4 + 3) * 64 + lane];
        }
        h = ln_silu(h, g_s[lane], be_s[lane]);

        if (FINAL) {
            float s = wred_sum(h * w2t_s[lane]);
            if (lane == 0) {
                float mask = (spec[atom] >= 0) ? 1.f : 0.f;
                dst[atom] = (s + b2_s[0]) * mask;
            }
        } else {
            h_s[wv][lane] = h;     // wave-private row
            int o = lane >> 3, seg = lane & 7;
            const float4* w2p = (const float4*)(w2t_s + o * 64 + seg * 8);
            const float4* hp  = (const float4*)(&h_s[wv][seg * 8]);
            float part = dot4(w2p[0], hp[0]) + dot4(w2p[1], hp[1]);
            part += __shfl_xor(part, 1, 64);
            part += __shfl_xor(part, 2, 64);
            part += __shfl_xor(part, 4, 64);
            if (seg == 0) {
                float val = part + b2_s[o];
                if (!PASS0) val += S_in[(size_t)atom * 8 + o];
                dst[(size_t)atom * 8 + o] = val;
            }
        }
    }
}

extern "C" void kernel_launch(void* const* d_in, const int* in_sizes, int n_in,
                              void* d_out, int out_size, void* d_ws, size_t ws_size,
                              hipStream_t stream) {
    const float* cart   = (const float*)d_in[0];
    const int*   aidx   = (const int*)d_in[1];
    const int*   spec   = (const int*)d_in[2];
    const float* ccoeff = (const float*)d_in[4];
    const float* embn_W1 = (const float*)d_in[5];
    const float* embn_b1 = (const float*)d_in[6];
    const float* embn_g  = (const float*)d_in[7];
    const float* embn_be = (const float*)d_in[8];
    const float* embn_W2 = (const float*)d_in[9];
    const float* embn_b2 = (const float*)d_in[10];
    const float* embc_W1 = (const float*)d_in[11];
    const float* embc_b1 = (const float*)d_in[12];
    const float* embc_g  = (const float*)d_in[13];
    const float* embc_be = (const float*)d_in[14];
    const float* embc_W2 = (const float*)d_in[15];
    const float* embc_b2 = (const float*)d_in[16];
    const float* oc_W1 = (const float*)d_in[17];
    const float* oc_b1 = (const float*)d_in[18];
    const float* oc_g  = (const float*)d_in[19];
    const float* oc_be = (const float*)d_in[20];
    const float* oc_W2 = (const float*)d_in[21];
    const float* oc_b2 = (const float*)d_in[22];
    const float* out_W1 = (const float*)d_in[23];
    const float* out_b1 = (const float*)d_in[24];
    const float* out_g  = (const float*)d_in[25];
    const float* out_be = (const float*)d_in[26];
    const float* out_W2 = (const float*)d_in[27];
    const float* out_b2 = (const float*)d_in[28];

    float* outp = (float*)d_out;

    char* ws = (char*)d_ws;
    size_t off = 0;
    auto carve = [&](size_t bytes) { size_t o = off; off = (off + bytes + 255) & ~(size_t)255; return o; };
    ushort_t* ang16 = (ushort_t*)(ws + carve((size_t)4 * NPADC * 2));
    ushort_t* rad16 = (ushort_t*)(ws + carve((size_t)8 * NPADC * 2));
    int*   keyv    = (int*)(ws + carve((size_t)NPADC * 4));
    int*   neigh   = (int*)(ws + carve((size_t)NPADC * 4));
    int*   plist   = (int*)(ws + carve((size_t)NPADC * 4));
    float* ccenter = (float*)(ws + carve((size_t)NATOMS * 64 * 4));
    float* co0     = (float*)(ws + carve((size_t)NATOMS * 32 * 4));
    float* cocur   = (float*)(ws + carve((size_t)NATOMS * 32 * 4));
    float* Sa      = (float*)(ws + carve((size_t)NATOMS * 8 * 4));
    float* Sb      = (float*)(ws + carve((size_t)NATOMS * 8 * 4));
    float* table   = (float*)(ws + carve((size_t)TBLN * 24 * 4));
    int*   cnt     = (int*)(ws + carve((size_t)NATOMS * 4));
    int*   offs    = (int*)(ws + carve((size_t)(NATOMS + 1) * 4));
    int*   cursor  = (int*)(ws + carve((size_t)NATOMS * 4));

    hipMemsetAsync(cnt, 0, (size_t)NATOMS * 4, stream);
    k_hist<<<NPAIRS / 256, 256, 0, stream>>>(aidx, cart, cnt, plist, outp);
    k_scan<<<1, 1024, 0, stream>>>(cnt, offs, cursor);
    k_scatter<<<NPAIRS / 256, 256, 0, stream>>>(aidx, cursor, plist);

    k_emb<<<CBLK + TBLK, 256, 0, stream>>>(spec,
                                           embc_W1, embc_b1, embc_g, embc_be, embc_W2, embc_b2,
                                           ccenter,
                                           embn_W1, embn_b1, embn_g, embn_be, embn_W2, embn_b2,
                                           table);

    k_pair2<<<NPADC / 256, 256, 0, stream>>>(cart, aidx, spec, table, plist, offs + NATOMS,
                                             ang16, rad16, keyv, neigh);

    // pass 0
    k_co<true><<<NATOMS / 8, 256, 0, stream>>>(offs, ang16, rad16, keyv, table, neigh,
                                               nullptr, nullptr, co0);
    k_mlp<true, false><<<NATOMS / AMLP, 256, 0, stream>>>(
        co0, ccenter, ccoeff + 0 * 1024, oc_W1 + 0 * 4096, oc_b1 + 0 * 64,
        oc_g + 0 * 64, oc_be + 0 * 64, oc_W2 + 0 * 512, oc_b2 + 0 * 8,
        nullptr, spec, Sa);
    // pass 1
    k_co<false><<<NATOMS / 8, 256, 0, stream>>>(offs, ang16, rad16, keyv, table, neigh,
                                                Sa, co0, cocur);
    k_mlp<false, false><<<NATOMS / AMLP, 256, 0, stream>>>(
        cocur, ccenter, ccoeff + 1 * 1024, oc_W1 + 1 * 4096, oc_b1 + 1 * 64,
        oc_g + 1 * 64, oc_be + 1 * 64, oc_W2 + 1 * 512, oc_b2 + 1 * 8,
        Sa, spec, Sb);
    // pass 2
    k_co<false><<<NATOMS / 8, 256, 0, stream>>>(offs, ang16, rad16, keyv, table, neigh,
                                                Sb, co0, cocur);
    k_mlp<false, false><<<NATOMS / AMLP, 256, 0, stream>>>(
        cocur, ccenter, ccoeff + 2 * 1024, oc_W1 + 2 * 4096, oc_b1 + 2 * 64,
        oc_g + 2 * 64, oc_be + 2 * 64, oc_W2 + 2 * 512, oc_b2 + 2 * 8,
        Sb, spec, Sa);
    // final
    k_co<false><<<NATOMS / 8, 256, 0, stream>>>(offs, ang16, rad16, keyv, table, neigh,
                                                Sa, co0, cocur);
    k_mlp<false, true><<<NATOMS / AMLP, 256, 0, stream>>>(
        cocur, ccenter, ccoeff + 3 * 1024, out_W1, out_b1, out_g, out_be,
        out_W2, out_b2, Sa, spec, outp + (size_t)NPAIRS * 3);
}